// Round 3
// baseline (707.106 us; speedup 1.0000x reference)
//
#include <hip/hip_runtime.h>

// HGNN+ conv: y = dv*(H * de*(H^T * (dv*(XW+b)))) + (XW+b)
// Pipeline (all on `stream`, no float atomics):
//   1. zero counts
//   2. GEMM: d_out = X*W + b   (x_mapped)
//   3. histogram edge/node degrees (int atomics)
//   4. hierarchical exclusive scan -> CSR starts (+ cursor copies)
//   5. scatter (counting sort) -> per-slot gather operands:
//        edge side: ecidx[s]=node, ecval[s]=hv*dv[node]
//        node side: ncidx[s]=edge, ncval[s]=hv
//   6. wave-per-edge gather: E2[e] = de[e] * sum ecval*xm[ecidx]
//   7. wave-per-node gather: y[n] = dv[n] * sum ncval*E2[ncidx] + xm[n]
// Gather kernels use split-wave float4 rows: lanes 0-31 even entries,
// lanes 32-63 odd entries, 4 features/lane, combined via shfl_xor(32).

#define F 128

__global__ void k_zero(int* __restrict__ p, int n) {
    int i = blockIdx.x * blockDim.x + threadIdx.x;
    if (i < n) p[i] = 0;
}

__global__ void k_hist(const int* __restrict__ ei, const int* __restrict__ ni,
                       int* __restrict__ ec, int* __restrict__ nc, int nnz) {
    int i = blockIdx.x * blockDim.x + threadIdx.x;
    if (i < nnz) {
        atomicAdd(&ec[ei[i]], 1);
        atomicAdd(&nc[ni[i]], 1);
    }
}

// block scans 1024 elements (256 thr x 4); per-element exclusive-within-block
// prefix to excl[], block total to part[blockIdx.x]
__global__ void k_scan1(const int* __restrict__ cnt, int* __restrict__ excl,
                        int* __restrict__ part, int n) {
    __shared__ int s[256];
    int t = threadIdx.x;
    int base = blockIdx.x * 1024 + t * 4;
    int v0 = (base + 0 < n) ? cnt[base + 0] : 0;
    int v1 = (base + 1 < n) ? cnt[base + 1] : 0;
    int v2 = (base + 2 < n) ? cnt[base + 2] : 0;
    int v3 = (base + 3 < n) ? cnt[base + 3] : 0;
    s[t] = v0 + v1 + v2 + v3;
    __syncthreads();
    for (int off = 1; off < 256; off <<= 1) {
        int add = (t >= off) ? s[t - off] : 0;
        __syncthreads();
        s[t] += add;
        __syncthreads();
    }
    int r = (t > 0) ? s[t - 1] : 0;
    if (base + 0 < n) excl[base + 0] = r; r += v0;
    if (base + 1 < n) excl[base + 1] = r; r += v1;
    if (base + 2 < n) excl[base + 2] = r; r += v2;
    if (base + 3 < n) excl[base + 3] = r;
    if (t == 255) part[blockIdx.x] = s[255];
}

// single block: exclusive scan of part[0..n), n <= 256
__global__ void k_scan2(int* __restrict__ part, int n) {
    __shared__ int s[256];
    int t = threadIdx.x;
    s[t] = (t < n) ? part[t] : 0;
    __syncthreads();
    for (int off = 1; off < 256; off <<= 1) {
        int add = (t >= off) ? s[t - off] : 0;
        __syncthreads();
        s[t] += add;
        __syncthreads();
    }
    if (t < n) part[t] = (t > 0) ? s[t - 1] : 0;
}

__global__ void k_scan3(int* __restrict__ start, int* __restrict__ cur,
                        const int* __restrict__ part, int n) {
    int i = blockIdx.x * blockDim.x + threadIdx.x;
    if (i < n) {
        int v = start[i] + part[i >> 10];
        start[i] = v;
        cur[i]   = v;
    }
}

// counting-sort scatter; materializes final gather operands per slot
__global__ void k_scatter(const int* __restrict__ ei, const int* __restrict__ ni,
                          const float* __restrict__ hv, const float* __restrict__ dv,
                          int* __restrict__ ecur, int* __restrict__ ncur,
                          int* __restrict__ ecidx, float* __restrict__ ecval,
                          int* __restrict__ ncidx, float* __restrict__ ncval, int nnz) {
    int i = blockIdx.x * blockDim.x + threadIdx.x;
    if (i < nnz) {
        int e = ei[i], nd = ni[i];
        float h = hv[i];
        int pe = atomicAdd(&ecur[e], 1);
        ecidx[pe] = nd;
        ecval[pe] = h * dv[nd];
        int pn = atomicAdd(&ncur[nd], 1);
        ncidx[pn] = e;
        ncval[pn] = h;
    }
}

__device__ __forceinline__ float f4_get(const float4& v, int k) {
    return k == 0 ? v.x : k == 1 ? v.y : k == 2 ? v.z : v.w;
}

// GEMM: y[N,128] = x[N,128] @ w[128,128] + bias. 128-row tile, 256 thr, 8x8/thread,
// K staged in 4 chunks of 32 (LDS: 16KB W-chunk + 18KB padded x-chunk).
__global__ __launch_bounds__(256) void k_gemm(const float* __restrict__ x,
                                              const float* __restrict__ w,
                                              const float* __restrict__ bias,
                                              float* __restrict__ y, int N) {
    __shared__ float sw[32 * 128];     // [k within chunk][c]
    __shared__ float sx[128 * 36];     // [r][k within chunk], padded
    int t = threadIdx.x;
    int row0 = blockIdx.x * 128;
    int cg = (t & 15) * 8;             // 8 output cols
    int rg = (t >> 4) * 8;             // 8 output rows (within tile)
    float acc[8][8];
#pragma unroll
    for (int a = 0; a < 8; a++)
#pragma unroll
        for (int b = 0; b < 8; b++) acc[a][b] = 0.f;

    const float4* x4 = (const float4*)x;
    const float4* w4 = (const float4*)w;

    for (int kc = 0; kc < 4; ++kc) {
        __syncthreads();
        for (int i = t; i < 1024; i += 256) {          // W chunk: 32 k x 128 c
            int k = i >> 5, c4 = i & 31;
            ((float4*)sw)[i] = w4[(kc * 32 + k) * 32 + c4];
        }
        for (int i = t; i < 1024; i += 256) {          // x chunk: 128 r x 32 k
            int r = i >> 3, c4 = i & 7;
            float4 vv = make_float4(0.f, 0.f, 0.f, 0.f);
            if (row0 + r < N) vv = x4[(size_t)(row0 + r) * 32 + kc * 8 + c4];
            *(float4*)&sx[r * 36 + c4 * 4] = vv;
        }
        __syncthreads();
#pragma unroll
        for (int k4 = 0; k4 < 8; ++k4) {
            float4 xa[8];
#pragma unroll
            for (int rr = 0; rr < 8; rr++)
                xa[rr] = *(const float4*)&sx[(rg + rr) * 36 + k4 * 4];
#pragma unroll
            for (int kk = 0; kk < 4; kk++) {
                float4 wa0 = *(const float4*)&sw[(k4 * 4 + kk) * 128 + cg];
                float4 wa1 = *(const float4*)&sw[(k4 * 4 + kk) * 128 + cg + 4];
#pragma unroll
                for (int rr = 0; rr < 8; rr++) {
                    float xv = f4_get(xa[rr], kk);
                    acc[rr][0] += xv * wa0.x; acc[rr][1] += xv * wa0.y;
                    acc[rr][2] += xv * wa0.z; acc[rr][3] += xv * wa0.w;
                    acc[rr][4] += xv * wa1.x; acc[rr][5] += xv * wa1.y;
                    acc[rr][6] += xv * wa1.z; acc[rr][7] += xv * wa1.w;
                }
            }
        }
    }

    float4 b0 = *(const float4*)&bias[cg];
    float4 b1 = *(const float4*)&bias[cg + 4];
#pragma unroll
    for (int rr = 0; rr < 8; rr++) {
        int r = row0 + rg + rr;
        if (r < N) {
            float4 o0 = make_float4(acc[rr][0] + b0.x, acc[rr][1] + b0.y,
                                    acc[rr][2] + b0.z, acc[rr][3] + b0.w);
            float4 o1 = make_float4(acc[rr][4] + b1.x, acc[rr][5] + b1.y,
                                    acc[rr][6] + b1.z, acc[rr][7] + b1.w);
            *(float4*)&y[(size_t)r * F + cg]     = o0;
            *(float4*)&y[(size_t)r * F + cg + 4] = o1;
        }
    }
}

// wave per hyperedge: E2[e][:] = de[e] * sum_s ecval[s] * xm[ecidx[s]][:]
// lanes 0-31: even entries, lanes 32-63: odd entries; 4 features/lane (float4)
__global__ __launch_bounds__(256) void k_edge(const float* __restrict__ xm,
                                              const int* __restrict__ cidx,
                                              const float* __restrict__ cval,
                                              const float* __restrict__ de,
                                              const int* __restrict__ start,
                                              const int* __restrict__ cnt,
                                              float* __restrict__ E2, int M) {
    int wid = blockIdx.x * 4 + (threadIdx.x >> 6);
    if (wid >= M) return;
    int lane = threadIdx.x & 63;
    int hl = lane >> 5;                 // entry parity handled by this half
    int l  = lane & 31;                 // feature group: floats 4l..4l+3
    int p = start[wid], c = cnt[wid];
    float a0 = 0.f, a1 = 0.f, a2 = 0.f, a3 = 0.f;
    int j = hl;
    for (; j + 2 < c; j += 4) {         // entries j and j+2 for this half
        int s0 = p + j, s1 = p + j + 2;
        int   n0 = cidx[s0], n1 = cidx[s1];
        float c0 = cval[s0], c1 = cval[s1];
        float4 v0 = *(const float4*)(xm + (size_t)n0 * F + l * 4);
        float4 v1 = *(const float4*)(xm + (size_t)n1 * F + l * 4);
        a0 += c0 * v0.x + c1 * v1.x;
        a1 += c0 * v0.y + c1 * v1.y;
        a2 += c0 * v0.z + c1 * v1.z;
        a3 += c0 * v0.w + c1 * v1.w;
    }
    if (j < c) {                        // at most one leftover per half
        int s0 = p + j;
        int n0 = cidx[s0];
        float c0 = cval[s0];
        float4 v0 = *(const float4*)(xm + (size_t)n0 * F + l * 4);
        a0 += c0 * v0.x; a1 += c0 * v0.y; a2 += c0 * v0.z; a3 += c0 * v0.w;
    }
    a0 += __shfl_xor(a0, 32);
    a1 += __shfl_xor(a1, 32);
    a2 += __shfl_xor(a2, 32);
    a3 += __shfl_xor(a3, 32);
    if (hl == 0) {
        float s = de[wid];
        *(float4*)(E2 + (size_t)wid * F + l * 4) =
            make_float4(a0 * s, a1 * s, a2 * s, a3 * s);
    }
}

// wave per node: y[n][:] = dv[n] * sum_s ncval[s]*E2[ncidx[s]][:] + xm[n][:]
// NOTE: xm and out alias (d_out) — wave reads only its own row before writing it.
__global__ __launch_bounds__(256) void k_node(const float* xm,
                                              const int* __restrict__ cidx,
                                              const float* __restrict__ cval,
                                              const float* __restrict__ dv,
                                              const int* __restrict__ start,
                                              const int* __restrict__ cnt,
                                              const float* __restrict__ E2,
                                              float* out, int N) {
    int wid = blockIdx.x * 4 + (threadIdx.x >> 6);
    if (wid >= N) return;
    int lane = threadIdx.x & 63;
    int hl = lane >> 5;
    int l  = lane & 31;
    int p = start[wid], c = cnt[wid];
    float a0 = 0.f, a1 = 0.f, a2 = 0.f, a3 = 0.f;
    int j = hl;
    for (; j + 2 < c; j += 4) {
        int s0 = p + j, s1 = p + j + 2;
        int   e0 = cidx[s0], e1 = cidx[s1];
        float c0 = cval[s0], c1 = cval[s1];
        float4 v0 = *(const float4*)(E2 + (size_t)e0 * F + l * 4);
        float4 v1 = *(const float4*)(E2 + (size_t)e1 * F + l * 4);
        a0 += c0 * v0.x + c1 * v1.x;
        a1 += c0 * v0.y + c1 * v1.y;
        a2 += c0 * v0.z + c1 * v1.z;
        a3 += c0 * v0.w + c1 * v1.w;
    }
    if (j < c) {
        int s0 = p + j;
        int e0 = cidx[s0];
        float c0 = cval[s0];
        float4 v0 = *(const float4*)(E2 + (size_t)e0 * F + l * 4);
        a0 += c0 * v0.x; a1 += c0 * v0.y; a2 += c0 * v0.z; a3 += c0 * v0.w;
    }
    a0 += __shfl_xor(a0, 32);
    a1 += __shfl_xor(a1, 32);
    a2 += __shfl_xor(a2, 32);
    a3 += __shfl_xor(a3, 32);
    if (hl == 0) {
        float dvn = dv[wid];
        float4 xv = *(const float4*)(xm + (size_t)wid * F + l * 4);
        *(float4*)(out + (size_t)wid * F + l * 4) =
            make_float4(a0 * dvn + xv.x, a1 * dvn + xv.y,
                        a2 * dvn + xv.z, a3 * dvn + xv.w);
    }
}

extern "C" void kernel_launch(void* const* d_in, const int* in_sizes, int n_in,
                              void* d_out, int out_size, void* d_ws, size_t ws_size,
                              hipStream_t stream) {
    const float* x      = (const float*)d_in[0];
    const float* w      = (const float*)d_in[1];
    const float* bias   = (const float*)d_in[2];
    const int*   ni     = (const int*)d_in[3];
    const int*   ei     = (const int*)d_in[4];
    const float* hv     = (const float*)d_in[5];
    const float* dv     = (const float*)d_in[6];
    const float* de     = (const float*)d_in[7];
    float* out = (float*)d_out;

    const int N   = in_sizes[0] / F;   // 100000
    const int NNZ = in_sizes[3];       // 1600000
    const int M   = in_sizes[7];       // 20000

    // workspace layout (4B units) — ~37.3 MB total
    int* wsp        = (int*)d_ws;
    int* edge_cnt   = wsp;                   // M
    int* node_cnt   = edge_cnt + M;          // N (contiguous with edge_cnt for k_zero)
    int* edge_start = node_cnt + N;          // M
    int* node_start = edge_start + M;        // N
    int* edge_cur   = node_start + N;        // M
    int* node_cur   = edge_cur + M;          // N
    int* partE      = node_cur + N;          // 256
    int* partN      = partE + 256;           // 256
    int* ecidx      = partN + 256;           // NNZ
    int* ncidx      = ecidx + NNZ;           // NNZ
    float* ecval    = (float*)(ncidx + NNZ); // NNZ
    float* ncval    = ecval + NNZ;           // NNZ
    float* E2       = ncval + NNZ;           // M*F

    const int gScanE = (M + 1023) / 1024;    // 20
    const int gScanN = (N + 1023) / 1024;    // 98

    k_zero<<<(M + N + 255) / 256, 256, 0, stream>>>(edge_cnt, M + N);
    k_gemm<<<(N + 127) / 128, 256, 0, stream>>>(x, w, bias, out, N);
    k_hist<<<(NNZ + 255) / 256, 256, 0, stream>>>(ei, ni, edge_cnt, node_cnt, NNZ);
    k_scan1<<<gScanE, 256, 0, stream>>>(edge_cnt, edge_start, partE, M);
    k_scan1<<<gScanN, 256, 0, stream>>>(node_cnt, node_start, partN, N);
    k_scan2<<<1, 256, 0, stream>>>(partE, gScanE);
    k_scan2<<<1, 256, 0, stream>>>(partN, gScanN);
    k_scan3<<<(M + 255) / 256, 256, 0, stream>>>(edge_start, edge_cur, partE, M);
    k_scan3<<<(N + 255) / 256, 256, 0, stream>>>(node_start, node_cur, partN, N);
    k_scatter<<<(NNZ + 255) / 256, 256, 0, stream>>>(ei, ni, hv, dv, edge_cur, node_cur,
                                                     ecidx, ecval, ncidx, ncval, NNZ);
    k_edge<<<(M + 3) / 4, 256, 0, stream>>>(out, ecidx, ecval, de,
                                            edge_start, edge_cnt, E2, M);
    k_node<<<(N + 3) / 4, 256, 0, stream>>>(out, ncidx, ncval, dv,
                                            node_start, node_cnt, E2, out, N);
}